// Round 1
// baseline (104.917 us; speedup 1.0000x reference)
//
#include <hip/hip_runtime.h>
#include <math.h>

#define Bn 32
#define Rn 512
#define Dn 256
#define Pn 5532
#define MAXU 512

typedef short short8 __attribute__((ext_vector_type(8)));
typedef short short4v __attribute__((ext_vector_type(4)));
typedef float floatx4 __attribute__((ext_vector_type(4)));

// ---- workspace layout (4-byte words). nll+tick zeroed by k1 block 33 each
// call; everything else read-after-write in-call (poison-safe).
#define XBF_OFF    0
#define XBF_WORDS  (Bn*Rn*Dn/2)
#define PBF_OFF    (XBF_OFF + XBF_WORDS)
#define PBF_WORDS  (Bn*MAXU*Dn/2)
#define LBLC_OFF   (PBF_OFF + PBF_WORDS)
#define CCNT_OFF   (LBLC_OFF + Bn*Rn)
#define CURS_OFF   (CCNT_OFF + Bn*MAXU)
#define RLIST_OFF  (CURS_OFF + Bn*MAXU)
#define NUNIQ_OFF  (RLIST_OFF + Bn*Rn)
#define NVALID_OFF (NUNIQ_OFF + 32)
#define NLL_OFF    (NVALID_OFF + 32)
#define TICK_OFF   (NLL_OFF + 1)
#define ZEROW      2                                  // nll + tick

__device__ __forceinline__ unsigned short bf16r(float f) {   // fp32 -> bf16 RNE
    union { float f; unsigned int u; } c; c.f = f;
    return (unsigned short)((c.u + 0x7FFFu + ((c.u >> 16) & 1u)) >> 16);
}
__device__ __forceinline__ float bfu2f(unsigned int hi16) {  // <<16'd bf16 -> f32
    union { unsigned int u; float f; } c; c.u = hi16;
    return c.f;
}

// async global->LDS, 16B per lane. LDS dest = wave-uniform base + lane*16.
__device__ __forceinline__ void async16(void* lds, const void* g) {
    auto* l3 = reinterpret_cast<__attribute__((address_space(3))) unsigned int*>(
                   reinterpret_cast<size_t>(lds));
    auto* g1 = reinterpret_cast<const __attribute__((address_space(1))) unsigned int*>(
                   reinterpret_cast<size_t>(g));
    __builtin_amdgcn_global_load_lds(g1, l3, 16, 0, 0);
}

// ==== k1: blocks 0..31 = in-LDS per-image compact; blocks 32..543 = convert+zero ====
__global__ __launch_bounds__(1024) void k1_prep(
    const float* __restrict__ inputs, const float* __restrict__ cls,
    const int* __restrict__ roi_label,
    unsigned short* __restrict__ xbf,
    int* __restrict__ lblc_arr, int* __restrict__ ccnt, int* __restrict__ cursor,
    int* __restrict__ rlist, int* __restrict__ nuniq, int* __restrict__ nvalid_arr,
    int* __restrict__ zbase)
{
    const int flat = blockIdx.x;
    const int t = threadIdx.x;

    __shared__ int cnt_lds[Pn];                       // 22.1 KB
    __shared__ int cmap_lds[Pn];                      // 22.1 KB
    __shared__ int curs_lds[MAXU];
    __shared__ int wpres[16], wcnt[16];

    if (flat >= 32) {
        // zero nll + tick
        if (flat == 33 && t < ZEROW) zbase[t] = 0;
        // convert inputs*cls -> bf16: 512 blocks x 1024 thr x 8 elems
        int g = (flat - 32) * 1024 + t;               // 0..524287
        int e = g * 8;
        int row = e >> 8;                             // /Dn
        float cw = cls[row];
        float4 v0 = *(const float4*)&inputs[e];
        float4 v1 = *(const float4*)&inputs[e + 4];
        short8 o;
        o[0] = (short)bf16r(v0.x * cw); o[1] = (short)bf16r(v0.y * cw);
        o[2] = (short)bf16r(v0.z * cw); o[3] = (short)bf16r(v0.w * cw);
        o[4] = (short)bf16r(v1.x * cw); o[5] = (short)bf16r(v1.y * cw);
        o[6] = (short)bf16r(v1.z * cw); o[7] = (short)bf16r(v1.w * cw);
        *(short8*)&xbf[e] = o;
        return;
    }

    // ---- per-image compact: counts from this image's 512 labels, all in LDS ----
    const int b = flat;
    const int lane = t & 63, wid = t >> 6;            // 16 waves
    for (int i = t; i < Pn; i += 1024) cnt_lds[i] = 0;
    __syncthreads();
    int mylbl = -1;
    if (t < Rn) {
        mylbl = roi_label[b * Rn + t] - 1;
        if (mylbl >= 0) atomicAdd(&cnt_lds[mylbl], 1);
    }
    __syncthreads();

    int basePres = 0, baseCnt = 0;                    // replicated in all threads
    for (int i0 = 0; i0 < Pn; i0 += 1024) {           // 6 chunks
        int i = i0 + t;
        int cnt = (i < Pn) ? cnt_lds[i] : 0;
        bool pres = cnt > 0;
        unsigned long long mask = __ballot(pres);
        int pfx_pres = __popcll(mask & ((1ULL << lane) - 1ULL));
        int v = cnt;
        #pragma unroll
        for (int off = 1; off < 64; off <<= 1) {
            int u = __shfl_up(v, off);
            if (lane >= off) v += u;
        }
        int pfx_cnt = v - cnt;                        // exclusive
        if (lane == 63) { wpres[wid] = __popcll(mask); wcnt[wid] = v; }
        __syncthreads();
        int woffP = 0, totP = 0, woffC = 0, totC = 0;
        #pragma unroll
        for (int w = 0; w < 16; ++w) {
            int p = wpres[w], c = wcnt[w];
            if (w < wid) { woffP += p; woffC += c; }
            totP += p; totC += c;
        }
        if (pres) {
            int c = basePres + woffP + pfx_pres;      // compact slot < MAXU
            cmap_lds[i] = c;
            ccnt[b * MAXU + c] = cnt;
            curs_lds[c] = baseCnt + woffC + pfx_cnt;  // start offset
        }
        basePres += totP; baseCnt += totC;
        __syncthreads();
    }
    // per-roi compact label + scatter to global rlist via LDS cursors
    if (t < Rn) {
        int lc = (mylbl >= 0) ? cmap_lds[mylbl] : -1;
        lblc_arr[b * Rn + t] = lc;
        if (lc >= 0) {
            int pos = atomicAdd(&curs_lds[lc], 1);
            rlist[b * Rn + pos] = t;
        }
    }
    __syncthreads();
    if (t < MAXU && t < basePres)
        cursor[b * MAXU + t] = curs_lds[t];           // end offset (= start + cnt)
    if (t == 0) { nuniq[b] = basePres; nvalid_arr[b] = baseCnt; }
}

// ==== k2: gather (bf16 xbf) -> mean -> L2 normalize -> bf16 proto (slot/WAVE) ====
__global__ __launch_bounds__(256) void k2_proto(
    const unsigned short* __restrict__ xbf,
    const int* __restrict__ nuniq, const int* __restrict__ ccnt,
    const int* __restrict__ cursor, const int* __restrict__ rlist,
    unsigned short* __restrict__ pbf)
{
    const int lane = threadIdx.x & 63, wv = threadIdx.x >> 6;
    int s = blockIdx.x * 4 + wv;                      // 4096 blocks -> 16384 slots
    int b = s >> 9;
    int c = s & (MAXU - 1);
    if (c >= nuniq[b]) return;
    int cnt = ccnt[s];
    int start = cursor[s] - cnt;
    float a0 = 0.f, a1 = 0.f, a2 = 0.f, a3 = 0.f;
    for (int k = 0; k < cnt; ++k) {
        int r = rlist[b * Rn + start + k];
        uint2 pk = *(const uint2*)&xbf[((size_t)(b * Rn + r)) * Dn + lane * 4];
        a0 += bfu2f(pk.x << 16); a1 += bfu2f(pk.x & 0xFFFF0000u);
        a2 += bfu2f(pk.y << 16); a3 += bfu2f(pk.y & 0xFFFF0000u);
    }
    float inv = 1.0f / (float)cnt;
    a0 *= inv; a1 *= inv; a2 *= inv; a3 *= inv;
    float ss = a0*a0 + a1*a1 + a2*a2 + a3*a3;
    #pragma unroll
    for (int off = 32; off > 0; off >>= 1) ss += __shfl_xor(ss, off);
    float scale = 1.0f / fmaxf(sqrtf(ss), 1e-12f);
    short4v o;
    o[0] = (short)bf16r(a0 * scale); o[1] = (short)bf16r(a1 * scale);
    o[2] = (short)bf16r(a2 * scale); o[3] = (short)bf16r(a3 * scale);
    *(short4v*)&pbf[(size_t)s * Dn + lane * 4] = o;
}

// ==== k3: 32 rois x ALL proto cols per block. Softmax denominator stays in
// registers across the internal pc loop -> no global sexp array, no atomic
// merge, no ticketed second pass, x staged once (was 4x).
// Logits bounded (|x.p| <= |x| ~ 16, p unit) -> exp without max-subtraction
// is safe in fp32 (R11-proven).
#define TRr 32
#define TCc 128
#define KCs 64
#define NSTG (Dn / KCs)                               // 4 stages per pc chunk
#define NBLK ((Rn / TRr) * Bn)                        // 512 blocks

__global__ __launch_bounds__(256, 3) void k3_loss(
    const unsigned short* __restrict__ xbf, const unsigned short* __restrict__ pbf,
    const int* __restrict__ lblc_arr, const int* __restrict__ nuniq,
    const int* __restrict__ nvalid_arr,
    float* __restrict__ nll, int* __restrict__ tick, float* __restrict__ out)
{
    // XOR-swizzled bf16 tiles (16B group g stored at gpos = g ^ (row&7)),
    // realized via per-lane GLOBAL address; LDS side stays lane*16-linear.
    __shared__ __align__(16) unsigned short xs[TRr * Dn];      // 16 KB, persistent
    __shared__ __align__(16) unsigned short ps[2][TCc * KCs];  // 2 x 16 KB dbuf
    __shared__ int lblc[TRr];
    __shared__ float esum_lds[4][TRr];
    __shared__ float dsum_lds[4][TRr];

    const int t = threadIdx.x;
    const int lane = t & 63, w = t >> 6;
    const int q = lane >> 4, r15 = lane & 15;
    const int rt = blockIdx.x;
    const int b  = blockIdx.y;
    const int roiBase = rt * TRr;
    const int U = nuniq[b];
    const int nch = (U <= 0) ? 1 : ((U + TCc - 1) >> 7);

    if (t < TRr) lblc[t] = lblc_arr[b * Rn + roiBase + t];

    // ---- stage x tile ONCE: 32 rows x 256 (32 groups/row, swizzle row&7) ----
    #pragma unroll
    for (int i = 0; i < 4; ++i) {
        int ci = i * 256 + w * 64 + lane;             // chunk 0..1023
        int row = ci >> 5, gpos = ci & 31;
        int g = gpos ^ (row & 7);
        async16(&xs[(i * 256 + w * 64) * 8],
                xbf + (size_t)(b * Rn + roiBase + row) * Dn + g * 8);
    }

    // ps stage: 128 cols x 64 K = 16 KB = 1024 chunks (8 groups/row)
#define ISSUE_PS(PC, ST, BUF)                                                \
    do {                                                                     \
        _Pragma("unroll")                                                    \
        for (int i_ = 0; i_ < 4; ++i_) {                                     \
            int ci_ = i_ * 256 + w * 64 + lane;                              \
            int pr_ = ci_ >> 3, gp_ = ci_ & 7;                               \
            int g_ = gp_ ^ (pr_ & 7);                                        \
            async16(&ps[BUF][(i_ * 256 + w * 64) * 8],                       \
                    pbf + (size_t)(b * MAXU + (PC) * TCc + pr_) * Dn         \
                        + (ST) * KCs + g_ * 8);                              \
        }                                                                    \
    } while (0)

    ISSUE_PS(0, 0, 0);
    __syncthreads();                                  // xs + ps[0] resident

    // preload all A fragments (rows = rois) into registers: 64 VGPRs
    short8 areg[2][8];
    #pragma unroll
    for (int mt = 0; mt < 2; ++mt)
        #pragma unroll
        for (int kcs = 0; kcs < 8; ++kcs) {
            int row = mt * 16 + r15;
            int gpos = (kcs * 4 + q) ^ (row & 7);
            areg[mt][kcs] = *(const short8*)&xs[row * Dn + gpos * 8];
        }

    int lcr[2][4];
    float esum[2][4], dsum[2][4];
    #pragma unroll
    for (int mt = 0; mt < 2; ++mt)
        #pragma unroll
        for (int reg = 0; reg < 4; ++reg) {
            lcr[mt][reg] = lblc[mt * 16 + q * 4 + reg];
            esum[mt][reg] = 0.f; dsum[mt][reg] = 0.f;
        }

    for (int pc = 0; pc < nch; ++pc) {
        floatx4 acc[2][2];
        #pragma unroll
        for (int mt = 0; mt < 2; ++mt) {
            acc[mt][0] = (floatx4)0.f; acc[mt][1] = (floatx4)0.f;
        }

        #pragma unroll
        for (int st = 0; st < NSTG; ++st) {
            const int cur = st & 1;                   // pc*4 even -> static parity
            __syncthreads();                          // ps[cur] resident
            int ns = pc * NSTG + st + 1;
            if (ns < nch * NSTG) ISSUE_PS(ns >> 2, ns & 3, cur ^ 1);
            #pragma unroll
            for (int kk = 0; kk < 2; ++kk) {
                short8 bb[2];
                #pragma unroll
                for (int nt = 0; nt < 2; ++nt) {
                    int r = w * 32 + nt * 16 + r15;
                    int gpos = (kk * 4 + q) ^ (r & 7);
                    bb[nt] = *(const short8*)&ps[cur][r * KCs + gpos * 8];
                }
                #pragma unroll
                for (int mt = 0; mt < 2; ++mt) {
                    acc[mt][0] = __builtin_amdgcn_mfma_f32_16x16x32_bf16(
                        areg[mt][st * 2 + kk], bb[0], acc[mt][0], 0, 0, 0);
                    acc[mt][1] = __builtin_amdgcn_mfma_f32_16x16x32_bf16(
                        areg[mt][st * 2 + kk], bb[1], acc[mt][1], 0, 0, 0);
                }
            }
        }

        // per-pc epilogue in registers; C/D: n = r15, m = q*4 + reg
        #pragma unroll
        for (int nt = 0; nt < 2; ++nt) {
            int c = pc * TCc + w * 32 + nt * 16 + r15;
            bool v = c < U;
            #pragma unroll
            for (int mt = 0; mt < 2; ++mt)
                #pragma unroll
                for (int reg = 0; reg < 4; ++reg) {
                    float d = acc[mt][nt][reg];
                    if (v) esum[mt][reg] += __expf(d);
                    if (c == lcr[mt][reg]) dsum[mt][reg] += d;  // lc < U always
                }
        }
    }
#undef ISSUE_PS

    // cross-lane (16) then cross-wave (LDS) combine; one atomic per block
    #pragma unroll
    for (int mt = 0; mt < 2; ++mt)
        #pragma unroll
        for (int reg = 0; reg < 4; ++reg) {
            float e = esum[mt][reg], d = dsum[mt][reg];
            #pragma unroll
            for (int off = 1; off < 16; off <<= 1) {
                e += __shfl_xor(e, off);
                d += __shfl_xor(d, off);
            }
            if (r15 == 0) {
                int row = mt * 16 + q * 4 + reg;
                esum_lds[w][row] = e;
                dsum_lds[w][row] = d;
            }
        }
    __syncthreads();
    if (t < TRr) {
        float es = esum_lds[0][t] + esum_lds[1][t] + esum_lds[2][t] + esum_lds[3][t];
        float ds = dsum_lds[0][t] + dsum_lds[1][t] + dsum_lds[2][t] + dsum_lds[3][t];
        float val = (lblc[t] >= 0) ? (__logf(es) - ds) : 0.f;
        #pragma unroll
        for (int off = 1; off < 32; off <<= 1) val += __shfl_xor(val, off);
        if (t == 0) {
            atomicAdd(nll, val);
            __threadfence();                          // order nll add vs ticket
            int old = atomicAdd(tick, 1);
            if (old == NBLK - 1) {                    // last block finalizes
                float total = atomicAdd(nll, 0.0f);   // coherent read
                int nv = 0;
                #pragma unroll
                for (int i = 0; i < Bn / 4; ++i) {
                    int4 vv = ((const int4*)nvalid_arr)[i];
                    nv += vv.x + vv.y + vv.z + vv.w;
                }
                out[0] = total / fmaxf((float)nv, 1.0f);
            }
        }
    }
}

extern "C" void kernel_launch(void* const* d_in, const int* in_sizes, int n_in,
                              void* d_out, int out_size, void* d_ws, size_t ws_size,
                              hipStream_t stream) {
    const float* inputs = (const float*)d_in[0];
    const float* cls    = (const float*)d_in[1];
    const int*   roi    = (const int*)d_in[2];
    float* out = (float*)d_out;

    float* wsf = (float*)d_ws;
    int*   wsi = (int*)d_ws;
    unsigned short* xbf = (unsigned short*)(wsi + XBF_OFF);
    unsigned short* pbf = (unsigned short*)(wsi + PBF_OFF);
    int*   lblc   = wsi + LBLC_OFF;
    int*   ccnt   = wsi + CCNT_OFF;
    int*   cursor = wsi + CURS_OFF;
    int*   rlist  = wsi + RLIST_OFF;
    int*   nuniq  = wsi + NUNIQ_OFF;
    int*   nvalid = wsi + NVALID_OFF;
    float* nll    = wsf + NLL_OFF;
    int*   tick   = wsi + TICK_OFF;

    k1_prep<<<32 + 512, 1024, 0, stream>>>(inputs, cls, roi, xbf, lblc, ccnt,
                                           cursor, rlist, nuniq, nvalid,
                                           wsi + NLL_OFF);
    k2_proto<<<(Bn * MAXU) / 4, 256, 0, stream>>>(xbf, nuniq, ccnt, cursor,
                                                  rlist, pbf);
    dim3 g(Rn / TRr, Bn);
    k3_loss<<<g, 256, 0, stream>>>(xbf, pbf, lblc, nuniq, nvalid, nll, tick, out);
}